// Round 9
// baseline (198.930 us; speedup 1.0000x reference)
//
#include <hip/hip_runtime.h>
#include <hip/hip_bf16.h>
#include <math.h>

#define N_DIM 128
#define NH 8
#define DKH 32
#define M_ROWS (N_DIM * N_DIM) // 16384

typedef __attribute__((ext_vector_type(8))) short bf16x8;
typedef __attribute__((ext_vector_type(4))) float f32x4;

__device__ inline ushort f2b(float x) {
    union { __hip_bfloat16 b; ushort u; } c;
    c.b = __float2bfloat16(x);
    return c.u;
}

#define GLDS(src, dst) \
    __builtin_amdgcn_global_load_lds((const __attribute__((address_space(1))) void*)(src), \
                                     (__attribute__((address_space(3))) void*)(dst), 16, 0, 0)

// ---------------------------------------------------------------------------
// prep: blocks [0,4096) bitpack the mask; blocks [4096,4352) convert weights.
// P [x*128+y] : z-bits of mask[x][y][:]   (PASS1 reads P[fixed*128 + row])
// PT[y*128+x] : same value, transposed    (PASS0 reads PT[fixed*128 + row])
// ---------------------------------------------------------------------------
__global__ __launch_bounds__(256) void prep_kernel(const int* __restrict__ mask,
                                                   ulonglong2* __restrict__ P,
                                                   ulonglong2* __restrict__ PT,
                                                   const float* __restrict__ w0,
                                                   const float* __restrict__ w1,
                                                   const float* __restrict__ w2,
                                                   const float* __restrict__ w3,
                                                   ushort* __restrict__ wout) {
    if (blockIdx.x < 4096) {
        const int row = blockIdx.x * 4 + (threadIdx.x >> 6); // 0..16383
        const int lane = threadIdx.x & 63;
        const int* mrow = mask + (size_t)row * 128;
        unsigned long long lo = __ballot(mrow[lane] != 0);
        unsigned long long hi = __ballot(mrow[64 + lane] != 0);
        if (lane == 0) {
            ulonglong2 v; v.x = lo; v.y = hi;
            P[row] = v;
            PT[(row & 127) * 128 + (row >> 7)] = v;
        }
    } else {
        const int b = blockIdx.x - 4096;   // 0..255
        const int m = b >> 6;
        const float* src = (m == 0) ? w0 : (m == 1) ? w1 : (m == 2) ? w2 : w3;
        const int off = (b & 63) * 1024 + threadIdx.x * 4;
        float4 v = *(const float4*)(src + off);
        union { ushort u[4]; short4 s4; } p;
        p.u[0] = f2b(v.x); p.u[1] = f2b(v.y); p.u[2] = f2b(v.z); p.u[3] = f2b(v.w);
        *(short4*)(wout + (size_t)m * 65536 + off) = p.s4;
    }
}

// ---------------------------------------------------------------------------
// One-shot GEMM: C[M][256] = A[M][256] @ W[256][256]^T, K=256, NO K-loop.
// BM=32 (blockIdx.x), BN=128 (blockIdx.y in {0,1}), 256 threads = 4 waves;
// wave w owns cols [w*32, +32). W col-slice staged in LDS (64 KB, 512B rows,
// 16B-chunk XOR swizzle c^=(row&7), via global_load_lds with inverse-swizzled
// source). A-fragments loaded global->reg directly (no A LDS, no 2nd barrier).
// AF32: A is f32 (cvt in regs). BATCHED: blockIdx.z selects input/W/out.
// ---------------------------------------------------------------------------
template <bool AF32, bool OBF16, bool BATCHED>
__global__ __launch_bounds__(256) void gemm3(const void* __restrict__ A0,
                                             const void* __restrict__ A1,
                                             const void* __restrict__ A2,
                                             const ushort* __restrict__ Wbase,
                                             void* __restrict__ Cbase,
                                             float oscale0) {
    __shared__ ushort Ws[128 * 256];   // 64 KB
    const int tid = threadIdx.x;
    const int w = tid >> 6, l = tid & 63;
    const int lr = l & 15, g = l >> 4;
    const int row0 = blockIdx.x * 32;
    const int col0 = blockIdx.y * 128;

    const void* Ain = A0;
    const ushort* W = Wbase;
    float oscale = oscale0;
    size_t coff = 0;
    if (BATCHED) {
        const int z = blockIdx.z;
        Ain = (z == 0) ? A0 : (z == 1) ? A1 : A2;
        W += (size_t)z * 65536;
        coff = (size_t)z * ((size_t)M_ROWS * 256);
        oscale = (z == 0) ? oscale0 : 1.0f;
    }

    // ---- stage W rows [col0, col0+128) x k[0,256): 16 GLDS per wave ----
    {
        const int lsub = l >> 5;          // row within pair
        const int lc31 = l & 31;          // 16B chunk within row
#pragma unroll
        for (int i = 0; i < 16; i++) {
            const int c2 = w * 16 + i;    // 0..63 -> local rows c2*2 + lsub
            const int r = c2 * 2 + lsub;
            GLDS(W + (size_t)(col0 + r) * 256 + ((lc31 ^ (r & 7)) * 8),
                 &Ws[c2 * 512]);
        }
    }
    __syncthreads();

    const float* Af = (const float*)Ain;
    const ushort* Ab = (const ushort*)Ain;

    f32x4 acc[2][2];
    const f32x4 zero = {0.f, 0.f, 0.f, 0.f};
    acc[0][0] = zero; acc[0][1] = zero; acc[1][0] = zero; acc[1][1] = zero;

#pragma unroll
    for (int ks = 0; ks < 8; ks++) {
        bf16x8 a[2];
#pragma unroll
        for (int fr = 0; fr < 2; fr++) {
            const size_t off = (size_t)(row0 + fr * 16 + lr) * 256 + ks * 32 + g * 8;
            if (AF32) {
                float4 v0 = *(const float4*)(Af + off);
                float4 v1 = *(const float4*)(Af + off + 4);
                union { ushort u[8]; bf16x8 b; } pk;
                pk.u[0] = f2b(v0.x); pk.u[1] = f2b(v0.y);
                pk.u[2] = f2b(v0.z); pk.u[3] = f2b(v0.w);
                pk.u[4] = f2b(v1.x); pk.u[5] = f2b(v1.y);
                pk.u[6] = f2b(v1.z); pk.u[7] = f2b(v1.w);
                a[fr] = pk.b;
            } else {
                a[fr] = *(const bf16x8*)(Ab + off);
            }
        }
#pragma unroll
        for (int fc = 0; fc < 2; fc++) {
            const int rw = w * 32 + fc * 16 + lr;
            bf16x8 b = *(const bf16x8*)((const char*)Ws + rw * 512 +
                                        (((ks * 4 + g) ^ (rw & 7)) * 16));
#pragma unroll
            for (int fr = 0; fr < 2; fr++)
                acc[fr][fc] = __builtin_amdgcn_mfma_f32_16x16x32_bf16(a[fr], b, acc[fr][fc], 0, 0, 0);
        }
    }

#pragma unroll
    for (int fr = 0; fr < 2; fr++)
#pragma unroll
        for (int fc = 0; fc < 2; fc++)
#pragma unroll
            for (int j = 0; j < 4; j++) {
                const int row = row0 + fr * 16 + g * 4 + j;
                const int col = col0 + w * 32 + fc * 16 + lr;
                const float vv = acc[fr][fc][j] * oscale;
                if (OBF16) ((ushort*)Cbase)[coff + (size_t)row * 256 + col] = f2b(vv);
                else       ((float*)Cbase)[(size_t)row * 256 + col] = vv;
            }
}

// ---------------------------------------------------------------------------
// Attention pass. PASS=0: l-half, block=(y,h), rows are x.
//                 PASS=1: r-half + combine, block=(x,h), rows are y.
// Q pre-scaled by 1/sqrt(32), loaded global->reg. Mask prepacked. Pl/ml/sl
// stored [x][h][y(,d)]: PASS0 scatter-writes, PASS1 reads contiguously into
// registers at kernel start (latency hidden under staging + MFMA).
// ---------------------------------------------------------------------------
template <int PASS>
__global__ __launch_bounds__(256) void attn_pass(const ushort* __restrict__ qb,
                                                 const ushort* __restrict__ kb,
                                                 const ushort* __restrict__ vb,
                                                 const ulonglong2* __restrict__ Pm,
                                                 float* __restrict__ ml,
                                                 float* __restrict__ sl,
                                                 float* __restrict__ Pl,
                                                 ushort* __restrict__ xb) {
    __shared__ ushort Ks[128 * 40];   // pitch 80 B
    __shared__ ushort Vt[32 * 128];   // [d][z], 256B rows, XOR swizzled
    __shared__ ushort Ats[128 * 128]; // [row][z], 256B rows, XOR swizzled
    __shared__ ulonglong2 Ms[128];    // bitpacked mask rows

    const int tid = threadIdx.x;
    const int fixed = blockIdx.x >> 3; // y (PASS0) or x (PASS1)
    const int h = blockIdx.x & 7;

    int base, stride;
    if (PASS == 0) {
        base = (fixed * NH + h) * DKH;
        stride = N_DIM * NH * DKH;
    } else {
        base = fixed * N_DIM * NH * DKH + h * DKH;
        stride = NH * DKH;
    }

    const int w = tid >> 6;
    const int lane = tid & 63;
    const int lr = lane & 15;
    const int g = lane >> 4;
    const int rbase = w * 32;

    // ---- early: mask bits, pass-0 stats + Pl into regs, Q frags ----
    if (tid < 128) Ms[tid] = Pm[fixed * 128 + tid];

    float plv[2][2][4], mlv_r[2][4], slv_r[2][4];
    if (PASS == 1) {
#pragma unroll
        for (int fr = 0; fr < 2; fr++)
#pragma unroll
            for (int j = 0; j < 4; j++) {
                const int row = rbase + fr * 16 + g * 4 + j;
                mlv_r[fr][j] = ml[(size_t)(fixed * NH + h) * N_DIM + row];
                slv_r[fr][j] = sl[(size_t)(fixed * NH + h) * N_DIM + row];
#pragma unroll
                for (int fc = 0; fc < 2; fc++) {
                    const int d = fc * 16 + lr;
                    plv[fr][fc][j] = Pl[((size_t)(fixed * NH + h) * N_DIM + row) * DKH + d];
                }
            }
    }

    bf16x8 aq[2];
#pragma unroll
    for (int fr = 0; fr < 2; fr++)
        aq[fr] = *(const bf16x8*)(qb + (size_t)base +
                                  (size_t)(rbase + fr * 16 + lr) * stride + g * 8);

    // ---- stage K, Vt (transpose + swizzle) ----
#pragma unroll
    for (int i = 0; i < 2; i++) {
        int idx = tid + i * 256;
        int r = idx >> 2, d0 = (idx & 3) * 8;
        size_t goff = (size_t)base + (size_t)r * stride + d0;
        int4 kv = *(const int4*)(kb + goff);
        *(int4*)&Ks[r * 40 + d0] = kv;
        union { int4 v4; ushort u[8]; } uu;
        uu.v4 = *(const int4*)(vb + goff);
#pragma unroll
        for (int j = 0; j < 8; j++) {
            int d = d0 + j;
            int byte = d * 256 + r * 2;
            byte ^= (d & 7) << 4;
            Vt[byte >> 1] = uu.u[j];
        }
    }
    __syncthreads();

    // ---- S = Q K^T (Q pre-scaled) ----
    f32x4 s[2][8];
    const f32x4 zero = {0.f, 0.f, 0.f, 0.f};
#pragma unroll
    for (int fc = 0; fc < 8; fc++) {
        bf16x8 bk = *(const bf16x8*)&Ks[(fc * 16 + lr) * 40 + g * 8];
#pragma unroll
        for (int fr = 0; fr < 2; fr++)
            s[fr][fc] = __builtin_amdgcn_mfma_f32_16x16x32_bf16(aq[fr], bk, zero, 0, 0, 0);
    }

    // ---- mask (bitpacked), row max, exp, row sum, att->LDS(bf16) ----
    float mx[2][4], sm[2][4];
#pragma unroll
    for (int fr = 0; fr < 2; fr++) {
#pragma unroll
        for (int j = 0; j < 4; j++) {
            const int row = rbase + fr * 16 + g * 4 + j;
            const ulonglong2 mb = Ms[row];
            const unsigned long long mls = mb.x >> lr;
            const unsigned long long mhs = mb.y >> lr;
            float mmax = -3.0e38f;
#pragma unroll
            for (int fc = 0; fc < 8; fc++) {
                const int bit = (int)(((fc < 4 ? mls : mhs) >> ((fc & 3) * 16)) & 1ull);
                float val = bit ? -1.0e9f : s[fr][fc][j];
                s[fr][fc][j] = val;
                mmax = fmaxf(mmax, val);
            }
            mmax = fmaxf(mmax, __shfl_xor(mmax, 1));
            mmax = fmaxf(mmax, __shfl_xor(mmax, 2));
            mmax = fmaxf(mmax, __shfl_xor(mmax, 4));
            mmax = fmaxf(mmax, __shfl_xor(mmax, 8));
            float ssum = 0.f;
#pragma unroll
            for (int fc = 0; fc < 8; fc++) {
                const int col = fc * 16 + lr;
                float e = __expf(s[fr][fc][j] - mmax);
                ssum += e;
                int byte = row * 256 + col * 2;
                byte ^= (row & 7) << 4;
                Ats[byte >> 1] = f2b(e);
            }
            ssum += __shfl_xor(ssum, 1);
            ssum += __shfl_xor(ssum, 2);
            ssum += __shfl_xor(ssum, 4);
            ssum += __shfl_xor(ssum, 8);
            mx[fr][j] = mmax;
            sm[fr][j] = ssum;
        }
    }
    __syncthreads();

    // ---- P = att @ V ----
    f32x4 p[2][2];
    p[0][0] = zero; p[0][1] = zero; p[1][0] = zero; p[1][1] = zero;
#pragma unroll
    for (int ks = 0; ks < 4; ks++) {
        bf16x8 pa[2];
#pragma unroll
        for (int fr = 0; fr < 2; fr++) {
            const int row = rbase + fr * 16 + lr;
            int byte = row * 256 + ks * 64 + g * 16;
            byte ^= (row & 7) << 4;
            pa[fr] = *(const bf16x8*)&Ats[byte >> 1];
        }
#pragma unroll
        for (int fc = 0; fc < 2; fc++) {
            const int rd = fc * 16 + lr;
            int byte = rd * 256 + ks * 64 + g * 16;
            byte ^= (rd & 7) << 4;
            bf16x8 vbf = *(const bf16x8*)&Vt[byte >> 1];
#pragma unroll
            for (int fr = 0; fr < 2; fr++)
                p[fr][fc] = __builtin_amdgcn_mfma_f32_16x16x32_bf16(pa[fr], vbf, p[fr][fc], 0, 0, 0);
        }
    }

    // ---- epilogue ----
    if (PASS == 0) {
        // scatter-store stats/PV in PASS1-friendly layout [x][h][y(,d)]
#pragma unroll
        for (int fr = 0; fr < 2; fr++) {
#pragma unroll
            for (int j = 0; j < 4; j++) {
                const int row = rbase + fr * 16 + g * 4 + j;   // x
                if (lr == 0) {
                    ml[((size_t)row * NH + h) * N_DIM + fixed] = mx[fr][j];
                    sl[((size_t)row * NH + h) * N_DIM + fixed] = sm[fr][j];
                }
#pragma unroll
                for (int fc = 0; fc < 2; fc++) {
                    const int d = fc * 16 + lr;
                    Pl[((size_t)(row * NH + h) * N_DIM + fixed) * DKH + d] = p[fr][fc][j];
                }
            }
        }
    } else {
#pragma unroll
        for (int fr = 0; fr < 2; fr++) {
#pragma unroll
            for (int j = 0; j < 4; j++) {
                const int row = rbase + fr * 16 + g * 4 + j;   // y
                const float mr = mx[fr][j], sr = sm[fr][j];
                const float mlv = mlv_r[fr][j], slv = slv_r[fr][j];
                const float m = fmaxf(mr, mlv);
                const float cr = __expf(mr - m), cl = __expf(mlv - m);
                const float inv = 1.0f / (sr * cr + slv * cl);
#pragma unroll
                for (int fc = 0; fc < 2; fc++) {
                    const int d = fc * 16 + lr;
                    const float o = (p[fr][fc][j] * cr + plv[fr][fc][j] * cl) * inv;
                    xb[((size_t)fixed * N_DIM + row) * 256 + h * DKH + d] = f2b(o);
                }
            }
        }
    }
}

extern "C" void kernel_launch(void* const* d_in, const int* in_sizes, int n_in,
                              void* d_out, int out_size, void* d_ws, size_t ws_size,
                              hipStream_t stream) {
    const float* query = (const float*)d_in[0];
    const float* key_t = (const float*)d_in[1];
    const float* value = (const float*)d_in[2];
    const int*   mask  = (const int*)d_in[3];
    const float* Wq    = (const float*)d_in[4];
    const float* Wk    = (const float*)d_in[5];
    const float* Wv    = (const float*)d_in[6];
    const float* Wo    = (const float*)d_in[7];

    const size_t MB = 1024 * 1024;
    char* ws = (char*)d_ws;
    ushort*     qb = (ushort*)ws;                       // 24 MB: q/k/v contiguous
    ushort*     kb = qb + (size_t)M_ROWS * 256;
    ushort*     vb = kb + (size_t)M_ROWS * 256;
    ushort*     xb = (ushort*)(ws + 24 * MB);           // 8 MB
    float*      Pl = (float*)(ws + 32 * MB);            // 16 MB
    float*      ml = (float*)(ws + 48 * MB);            // 512 KB
    float*      sl = (float*)(ws + 48 * MB + 512 * 1024);
    ushort*     Wb = (ushort*)(ws + 49 * MB);           // 512 KB
    ulonglong2* Pp = (ulonglong2*)(ws + 50 * MB);       // 256 KB  [x][y]
    ulonglong2* PT = (ulonglong2*)(ws + 50 * MB + 256 * 1024); // 256 KB [y][x]

    const float qscale = 0.17677669529663687f; // 1/sqrt(32)

    prep_kernel<<<4352, 256, 0, stream>>>(mask, Pp, PT, Wq, Wk, Wv, Wo, Wb);
    gemm3<true, true, true><<<dim3(M_ROWS / 32, 2, 3), 256, 0, stream>>>(
        query, key_t, value, Wb, qb, qscale);
    attn_pass<0><<<N_DIM * NH, 256, 0, stream>>>(qb, kb, vb, PT, ml, sl, Pl, xb);
    attn_pass<1><<<N_DIM * NH, 256, 0, stream>>>(qb, kb, vb, Pp, ml, sl, Pl, xb);
    gemm3<false, false, false><<<dim3(M_ROWS / 32, 2, 1), 256, 0, stream>>>(
        xb, nullptr, nullptr, Wb + 3 * 65536, d_out, 1.0f);
}

// Round 10
// 171.184 us; speedup vs baseline: 1.1621x; 1.1621x over previous
//
#include <hip/hip_runtime.h>
#include <hip/hip_bf16.h>
#include <math.h>

#define N_DIM 128
#define NH 8
#define DKH 32
#define M_ROWS (N_DIM * N_DIM) // 16384

typedef __attribute__((ext_vector_type(8))) short bf16x8;
typedef __attribute__((ext_vector_type(4))) float f32x4;

__device__ inline ushort f2b(float x) {
    union { __hip_bfloat16 b; ushort u; } c;
    c.b = __float2bfloat16(x);
    return c.u;
}

// involutive bank swizzle for 64B-row LDS tiles (uses bits 7-8, flips bits 4-5)
__device__ inline int swz64(int b) { return b ^ (((b >> 7) & 3) << 4); }

#define GLDS(src, dst) \
    __builtin_amdgcn_global_load_lds((const __attribute__((address_space(1))) void*)(src), \
                                     (__attribute__((address_space(3))) void*)(dst), 16, 0, 0)

// ---------------------------------------------------------------------------
// prep: blocks [0,4096) bitpack the mask; blocks [4096,4352) convert weights.
// ---------------------------------------------------------------------------
__global__ __launch_bounds__(256) void prep_kernel(const int* __restrict__ mask,
                                                   ulonglong2* __restrict__ P,
                                                   ulonglong2* __restrict__ PT,
                                                   const float* __restrict__ w0,
                                                   const float* __restrict__ w1,
                                                   const float* __restrict__ w2,
                                                   const float* __restrict__ w3,
                                                   ushort* __restrict__ wout) {
    if (blockIdx.x < 4096) {
        const int row = blockIdx.x * 4 + (threadIdx.x >> 6); // 0..16383
        const int lane = threadIdx.x & 63;
        const int* mrow = mask + (size_t)row * 128;
        unsigned long long lo = __ballot(mrow[lane] != 0);
        unsigned long long hi = __ballot(mrow[64 + lane] != 0);
        if (lane == 0) {
            ulonglong2 v; v.x = lo; v.y = hi;
            P[row] = v;
            PT[(row & 127) * 128 + (row >> 7)] = v;
        }
    } else {
        const int b = blockIdx.x - 4096;   // 0..255
        const int m = b >> 6;
        const float* src = (m == 0) ? w0 : (m == 1) ? w1 : (m == 2) ? w2 : w3;
        const int off = (b & 63) * 1024 + threadIdx.x * 4;
        float4 v = *(const float4*)(src + off);
        union { ushort u[4]; short4 s4; } p;
        p.u[0] = f2b(v.x); p.u[1] = f2b(v.y); p.u[2] = f2b(v.z); p.u[3] = f2b(v.w);
        *(short4*)(wout + (size_t)m * 65536 + off) = p.s4;
    }
}

// ---------------------------------------------------------------------------
// gemm5: C[M][256] = A[M][256] @ W[256][256]^T via mfma 16x16x32 bf16.
// BM=64, BN=256, BK=32, 512 threads = 8 waves (2M x 4N), dbuf LDS 40KB
// -> 4 blocks/CU. LDS rows are 64B; swz64 spreads fragment reads across
// 8 bank groups (involution). W (and bf16 A) staged via global_load_lds
// with inverse-swizzled SOURCE + linear dest; f32 A reg-staged with cvt
// writing to the swizzled address. Reads apply the same swizzle.
// ---------------------------------------------------------------------------
template <bool AF32, bool OBF16, bool BATCHED>
__global__ __launch_bounds__(512) void gemm5(const void* __restrict__ A0,
                                             const void* __restrict__ A1,
                                             const void* __restrict__ A2,
                                             const ushort* __restrict__ Wbase,
                                             void* __restrict__ Cbase,
                                             float oscale0) {
    __shared__ ushort As[2][64 * 32];    // 4 KB per buf
    __shared__ ushort Ws[2][256 * 32];   // 16 KB per buf
    const int tid = threadIdx.x;
    const int w = tid >> 6, l = tid & 63;
    const int lr = l & 15, g = l >> 4;
    const int wm = w & 1, wn = w >> 1;   // 2M x 4N wave grid
    const int row0 = blockIdx.x * 64;

    const void* Ain = A0;
    const ushort* W = Wbase;
    float oscale = oscale0;
    size_t coff = 0;
    if (BATCHED) {
        const int z = blockIdx.z;
        Ain = (z == 0) ? A0 : (z == 1) ? A1 : A2;
        W += (size_t)z * 65536;
        coff = (size_t)z * ((size_t)M_ROWS * 256);
        oscale = (z == 0) ? oscale0 : 1.0f;
    }

    auto stage = [&](int t, int buf) {
        const int kbase = t * 32;
        // W tile: 256 rows x 32 k = 16 KB = 16 chunks of 1KB; wave w stages 2.
#pragma unroll
        for (int i = 0; i < 2; i++) {
            const int c = w * 2 + i;
            const int lsw = swz64(c * 1024 + l * 16);      // logical byte
            GLDS(W + (size_t)(lsw >> 6) * 256 + kbase + ((lsw & 63) >> 1),
                 &Ws[buf][c * 512]);
        }
        if (AF32) {
            // A tile 64 x 32: f32 source, cvt in regs, swizzled ds_write_b64
            const float* Af = (const float*)Ain;
            const int rr = tid >> 3, k4 = (tid & 7) * 4;
            float4 v = *(const float4*)(Af + (size_t)(row0 + rr) * 256 + kbase + k4);
            union { ushort u[4]; short4 s4; } p;
            p.u[0] = f2b(v.x); p.u[1] = f2b(v.y); p.u[2] = f2b(v.z); p.u[3] = f2b(v.w);
            *(short4*)((char*)&As[buf][0] + swz64(rr * 64 + k4 * 2)) = p.s4;
        } else {
            // A tile 64 x 32 bf16 = 4 KB = 4 chunks; waves 0..3 stage 1 each.
            if (w < 4) {
                const ushort* Ab = (const ushort*)Ain;
                const int lsw = swz64(w * 1024 + l * 16);
                GLDS(Ab + (size_t)(row0 + (lsw >> 6)) * 256 + kbase + ((lsw & 63) >> 1),
                     &As[buf][w * 512]);
            }
        }
    };

    f32x4 acc[2][4];
    const f32x4 zero = {0.f, 0.f, 0.f, 0.f};
#pragma unroll
    for (int fr = 0; fr < 2; fr++)
#pragma unroll
        for (int fc = 0; fc < 4; fc++) acc[fr][fc] = zero;

    stage(0, 0);
    __syncthreads();

#pragma unroll
    for (int t = 0; t < 8; t++) {
        const int cur = t & 1;
        if (t < 7) stage(t + 1, cur ^ 1);
        bf16x8 a[2], bw[4];
#pragma unroll
        for (int fr = 0; fr < 2; fr++) {
            const int lb = (wm * 32 + fr * 16 + lr) * 64 + g * 16;
            a[fr] = *(const bf16x8*)((const char*)&As[cur][0] + swz64(lb));
        }
#pragma unroll
        for (int fc = 0; fc < 4; fc++) {
            const int lb = (wn * 64 + fc * 16 + lr) * 64 + g * 16;
            bw[fc] = *(const bf16x8*)((const char*)&Ws[cur][0] + swz64(lb));
        }
#pragma unroll
        for (int fr = 0; fr < 2; fr++)
#pragma unroll
            for (int fc = 0; fc < 4; fc++)
                acc[fr][fc] = __builtin_amdgcn_mfma_f32_16x16x32_bf16(a[fr], bw[fc], acc[fr][fc], 0, 0, 0);
        __syncthreads();
    }

#pragma unroll
    for (int fr = 0; fr < 2; fr++)
#pragma unroll
        for (int fc = 0; fc < 4; fc++)
#pragma unroll
            for (int j = 0; j < 4; j++) {
                const int row = row0 + wm * 32 + fr * 16 + g * 4 + j;
                const int col = wn * 64 + fc * 16 + lr;
                const float vv = acc[fr][fc][j] * oscale;
                if (OBF16) ((ushort*)Cbase)[coff + (size_t)row * 256 + col] = f2b(vv);
                else       ((float*)Cbase)[(size_t)row * 256 + col] = vv;
            }
}

// ---------------------------------------------------------------------------
// Attention pass. PASS=0: l-half, block=(y,h), rows are x.
//                 PASS=1: r-half + combine, block=(x,h), rows are y.
// Q pre-scaled by 1/sqrt(32), loaded global->reg. Mask prepacked. Pl/ml/sl
// stored [x][h][y(,d)]: PASS0 scatter-writes, PASS1 reads contiguously into
// registers at kernel start (latency hidden under staging + MFMA).
// ---------------------------------------------------------------------------
template <int PASS>
__global__ __launch_bounds__(256) void attn_pass(const ushort* __restrict__ qb,
                                                 const ushort* __restrict__ kb,
                                                 const ushort* __restrict__ vb,
                                                 const ulonglong2* __restrict__ Pm,
                                                 float* __restrict__ ml,
                                                 float* __restrict__ sl,
                                                 float* __restrict__ Pl,
                                                 ushort* __restrict__ xb) {
    __shared__ ushort Ks[128 * 40];   // pitch 80 B
    __shared__ ushort Vt[32 * 128];   // [d][z], 256B rows, XOR swizzled
    __shared__ ushort Ats[128 * 128]; // [row][z], 256B rows, XOR swizzled
    __shared__ ulonglong2 Ms[128];    // bitpacked mask rows

    const int tid = threadIdx.x;
    const int fixed = blockIdx.x >> 3; // y (PASS0) or x (PASS1)
    const int h = blockIdx.x & 7;

    int base, stride;
    if (PASS == 0) {
        base = (fixed * NH + h) * DKH;
        stride = N_DIM * NH * DKH;
    } else {
        base = fixed * N_DIM * NH * DKH + h * DKH;
        stride = NH * DKH;
    }

    const int w = tid >> 6;
    const int lane = tid & 63;
    const int lr = lane & 15;
    const int g = lane >> 4;
    const int rbase = w * 32;

    // ---- early: mask bits, pass-0 stats + Pl into regs, Q frags ----
    if (tid < 128) Ms[tid] = Pm[fixed * 128 + tid];

    float plv[2][2][4], mlv_r[2][4], slv_r[2][4];
    if (PASS == 1) {
#pragma unroll
        for (int fr = 0; fr < 2; fr++)
#pragma unroll
            for (int j = 0; j < 4; j++) {
                const int row = rbase + fr * 16 + g * 4 + j;
                mlv_r[fr][j] = ml[(size_t)(fixed * NH + h) * N_DIM + row];
                slv_r[fr][j] = sl[(size_t)(fixed * NH + h) * N_DIM + row];
#pragma unroll
                for (int fc = 0; fc < 2; fc++) {
                    const int d = fc * 16 + lr;
                    plv[fr][fc][j] = Pl[((size_t)(fixed * NH + h) * N_DIM + row) * DKH + d];
                }
            }
    }

    bf16x8 aq[2];
#pragma unroll
    for (int fr = 0; fr < 2; fr++)
        aq[fr] = *(const bf16x8*)(qb + (size_t)base +
                                  (size_t)(rbase + fr * 16 + lr) * stride + g * 8);

    // ---- stage K, Vt (transpose + swizzle) ----
#pragma unroll
    for (int i = 0; i < 2; i++) {
        int idx = tid + i * 256;
        int r = idx >> 2, d0 = (idx & 3) * 8;
        size_t goff = (size_t)base + (size_t)r * stride + d0;
        int4 kv = *(const int4*)(kb + goff);
        *(int4*)&Ks[r * 40 + d0] = kv;
        union { int4 v4; ushort u[8]; } uu;
        uu.v4 = *(const int4*)(vb + goff);
#pragma unroll
        for (int j = 0; j < 8; j++) {
            int d = d0 + j;
            int byte = d * 256 + r * 2;
            byte ^= (d & 7) << 4;
            Vt[byte >> 1] = uu.u[j];
        }
    }
    __syncthreads();

    // ---- S = Q K^T (Q pre-scaled) ----
    f32x4 s[2][8];
    const f32x4 zero = {0.f, 0.f, 0.f, 0.f};
#pragma unroll
    for (int fc = 0; fc < 8; fc++) {
        bf16x8 bk = *(const bf16x8*)&Ks[(fc * 16 + lr) * 40 + g * 8];
#pragma unroll
        for (int fr = 0; fr < 2; fr++)
            s[fr][fc] = __builtin_amdgcn_mfma_f32_16x16x32_bf16(aq[fr], bk, zero, 0, 0, 0);
    }

    // ---- mask (bitpacked), row max, exp, row sum, att->LDS(bf16) ----
    float mx[2][4], sm[2][4];
#pragma unroll
    for (int fr = 0; fr < 2; fr++) {
#pragma unroll
        for (int j = 0; j < 4; j++) {
            const int row = rbase + fr * 16 + g * 4 + j;
            const ulonglong2 mb = Ms[row];
            const unsigned long long mls = mb.x >> lr;
            const unsigned long long mhs = mb.y >> lr;
            float mmax = -3.0e38f;
#pragma unroll
            for (int fc = 0; fc < 8; fc++) {
                const int bit = (int)(((fc < 4 ? mls : mhs) >> ((fc & 3) * 16)) & 1ull);
                float val = bit ? -1.0e9f : s[fr][fc][j];
                s[fr][fc][j] = val;
                mmax = fmaxf(mmax, val);
            }
            mmax = fmaxf(mmax, __shfl_xor(mmax, 1));
            mmax = fmaxf(mmax, __shfl_xor(mmax, 2));
            mmax = fmaxf(mmax, __shfl_xor(mmax, 4));
            mmax = fmaxf(mmax, __shfl_xor(mmax, 8));
            float ssum = 0.f;
#pragma unroll
            for (int fc = 0; fc < 8; fc++) {
                const int col = fc * 16 + lr;
                float e = __expf(s[fr][fc][j] - mmax);
                ssum += e;
                int byte = row * 256 + col * 2;
                byte ^= (row & 7) << 4;
                Ats[byte >> 1] = f2b(e);
            }
            ssum += __shfl_xor(ssum, 1);
            ssum += __shfl_xor(ssum, 2);
            ssum += __shfl_xor(ssum, 4);
            ssum += __shfl_xor(ssum, 8);
            mx[fr][j] = mmax;
            sm[fr][j] = ssum;
        }
    }
    __syncthreads();

    // ---- P = att @ V ----
    f32x4 p[2][2];
    p[0][0] = zero; p[0][1] = zero; p[1][0] = zero; p[1][1] = zero;
#pragma unroll
    for (int ks = 0; ks < 4; ks++) {
        bf16x8 pa[2];
#pragma unroll
        for (int fr = 0; fr < 2; fr++) {
            const int row = rbase + fr * 16 + lr;
            int byte = row * 256 + ks * 64 + g * 16;
            byte ^= (row & 7) << 4;
            pa[fr] = *(const bf16x8*)&Ats[byte >> 1];
        }
#pragma unroll
        for (int fc = 0; fc < 2; fc++) {
            const int rd = fc * 16 + lr;
            int byte = rd * 256 + ks * 64 + g * 16;
            byte ^= (rd & 7) << 4;
            bf16x8 vbf = *(const bf16x8*)&Vt[byte >> 1];
#pragma unroll
            for (int fr = 0; fr < 2; fr++)
                p[fr][fc] = __builtin_amdgcn_mfma_f32_16x16x32_bf16(pa[fr], vbf, p[fr][fc], 0, 0, 0);
        }
    }

    // ---- epilogue ----
    if (PASS == 0) {
#pragma unroll
        for (int fr = 0; fr < 2; fr++) {
#pragma unroll
            for (int j = 0; j < 4; j++) {
                const int row = rbase + fr * 16 + g * 4 + j;   // x
                if (lr == 0) {
                    ml[((size_t)row * NH + h) * N_DIM + fixed] = mx[fr][j];
                    sl[((size_t)row * NH + h) * N_DIM + fixed] = sm[fr][j];
                }
#pragma unroll
                for (int fc = 0; fc < 2; fc++) {
                    const int d = fc * 16 + lr;
                    Pl[((size_t)(row * NH + h) * N_DIM + fixed) * DKH + d] = p[fr][fc][j];
                }
            }
        }
    } else {
#pragma unroll
        for (int fr = 0; fr < 2; fr++) {
#pragma unroll
            for (int j = 0; j < 4; j++) {
                const int row = rbase + fr * 16 + g * 4 + j;   // y
                const float mr = mx[fr][j], sr = sm[fr][j];
                const float mlv = mlv_r[fr][j], slv = slv_r[fr][j];
                const float m = fmaxf(mr, mlv);
                const float cr = __expf(mr - m), cl = __expf(mlv - m);
                const float inv = 1.0f / (sr * cr + slv * cl);
#pragma unroll
                for (int fc = 0; fc < 2; fc++) {
                    const int d = fc * 16 + lr;
                    const float o = (p[fr][fc][j] * cr + plv[fr][fc][j] * cl) * inv;
                    xb[((size_t)fixed * N_DIM + row) * 256 + h * DKH + d] = f2b(o);
                }
            }
        }
    }
}

extern "C" void kernel_launch(void* const* d_in, const int* in_sizes, int n_in,
                              void* d_out, int out_size, void* d_ws, size_t ws_size,
                              hipStream_t stream) {
    const float* query = (const float*)d_in[0];
    const float* key_t = (const float*)d_in[1];
    const float* value = (const float*)d_in[2];
    const int*   mask  = (const int*)d_in[3];
    const float* Wq    = (const float*)d_in[4];
    const float* Wk    = (const float*)d_in[5];
    const float* Wv    = (const float*)d_in[6];
    const float* Wo    = (const float*)d_in[7];

    const size_t MB = 1024 * 1024;
    char* ws = (char*)d_ws;
    ushort*     qb = (ushort*)ws;                       // 24 MB: q/k/v contiguous
    ushort*     kb = qb + (size_t)M_ROWS * 256;
    ushort*     vb = kb + (size_t)M_ROWS * 256;
    ushort*     xb = (ushort*)(ws + 24 * MB);           // 8 MB
    float*      Pl = (float*)(ws + 32 * MB);            // 16 MB
    float*      ml = (float*)(ws + 48 * MB);            // 512 KB
    float*      sl = (float*)(ws + 48 * MB + 512 * 1024);
    ushort*     Wb = (ushort*)(ws + 49 * MB);           // 512 KB
    ulonglong2* Pp = (ulonglong2*)(ws + 50 * MB);       // 256 KB  [x][y]
    ulonglong2* PT = (ulonglong2*)(ws + 50 * MB + 256 * 1024); // 256 KB [y][x]

    const float qscale = 0.17677669529663687f; // 1/sqrt(32)

    prep_kernel<<<4352, 256, 0, stream>>>(mask, Pp, PT, Wq, Wk, Wv, Wo, Wb);
    gemm5<true, true, true><<<dim3(M_ROWS / 64, 1, 3), 512, 0, stream>>>(
        query, key_t, value, Wb, qb, qscale);
    attn_pass<0><<<N_DIM * NH, 256, 0, stream>>>(qb, kb, vb, PT, ml, sl, Pl, xb);
    attn_pass<1><<<N_DIM * NH, 256, 0, stream>>>(qb, kb, vb, Pp, ml, sl, Pl, xb);
    gemm5<false, false, false><<<dim3(M_ROWS / 64, 1, 1), 512, 0, stream>>>(
        xb, nullptr, nullptr, Wb + 3 * 65536, d_out, 1.0f);
}